// Round 11
// baseline (152.142 us; speedup 1.0000x reference)
//
#include <hip/hip_runtime.h>
#include <hip/hip_bf16.h>
#include <stdint.h>

#define BATCH 8192
#define IN    1024
#define OUTD  1024
#define PBASIS 8

typedef __attribute__((ext_vector_type(8))) short bf16x8;
typedef __attribute__((ext_vector_type(4))) float floatx4;

__device__ __forceinline__ unsigned short f2bf(float f) {
    union { float f; unsigned u; } v; v.f = f;
    unsigned u = v.u;
    u += 0x7fffu + ((u >> 16) & 1u);   // RNE; inputs finite randn
    return (unsigned short)(u >> 16);
}

// v_cvt_pk_bf16_f32: packs 2 f32 -> 2 bf16 (RNE), S0 -> low 16. Bit-identical
// to f2bf for finite inputs. No builtin on gfx950 [m240] -> inline asm.
__device__ __forceinline__ unsigned cvtpk(float lo, float hi) {
    unsigned r;
    asm("v_cvt_pk_bf16_f32 %0, %1, %2" : "=v"(r) : "v"(lo), "v"(hi));
    return r;
}

__device__ __forceinline__ bf16x8 mkbf8(float4 lo, float4 hi) {
    union { uint4 u; bf16x8 b; } x;
    x.u.x = cvtpk(lo.x, lo.y);
    x.u.y = cvtpk(lo.z, lo.w);
    x.u.z = cvtpk(hi.x, hi.y);
    x.u.w = cvtpk(hi.z, hi.w);
    return x.b;
}

// prep: w_eff = bf16(sum_p coef * w), 2 elems/thread. 38 MB HBM (~6 us).
__global__ void prep_kernel(const float* __restrict__ coef,
                            const float* __restrict__ w,
                            unsigned short* __restrict__ weff) {
    int idx = blockIdx.x * 256 + threadIdx.x;    // element pair index
    size_t e0 = (size_t)idx * 2;
    const float4* c4 = (const float4*)(coef + e0 * PBASIS);
    float4 a = c4[0], bb = c4[1], c = c4[2], d = c4[3];
    float s0 = (a.x + a.y + a.z + a.w) + (bb.x + bb.y + bb.z + bb.w);
    float s1 = (c.x + c.y + c.z + c.w) + (d.x + d.y + d.z + d.w);
    float2 ww = ((const float2*)w)[idx];
    unsigned b0 = f2bf(s0 * ww.x);
    unsigned b1 = f2bf(s1 * ww.y);
    ((unsigned*)weff)[idx] = b0 | (b1 << 16);
}

__device__ __forceinline__ void gload_lds16(const void* g, void* l) {
    __builtin_amdgcn_global_load_lds(
        (const __attribute__((address_space(1))) unsigned int*)g,
        (__attribute__((address_space(3))) unsigned int*)l,
        16, 0, 0);
}

// Raw barrier + counted waits: loads stay in flight across barriers.
#define BARRIER()   asm volatile("s_barrier" ::: "memory")
#define WAIT_V6L0() asm volatile("s_waitcnt vmcnt(6) lgkmcnt(0)" ::: "memory")
#define WAIT_V0L0() asm volatile("s_waitcnt vmcnt(0) lgkmcnt(0)" ::: "memory")

// C[m,n] = sum_k x[m,k]*B[n,k]; x=[8192,1024] f32, B=[1024,1024] bf16.
//
// R11: x-fusion WITHOUT per-lane VMEM consumers. Lesson from R6/R8/R9/R10
// (all 46-49us, MfmaUtil ~12%): any staging path where a VALU/LDS op
// consumes a per-lane global load result lets the compiler sink the load
// to its use (VGPR=100 evidence) -> synchronous prefetch. Only
// global_load_lds (fire-and-forget) stays issued-early. So: stage A as
// RAW F32 via gload_lds; convert f32->bf16 at LDS->reg fragment-read time
// (v_cvt_pk_bf16_f32, RNE == old prep's f2bf => identical values).
//
// Geometry: BM=128 x BN=128, BK=64, 512 thr = 8 waves (2M x 4N), wave
// tile 64x32, acc[4][2]. Stage = A 32KB f32 + B 16KB bf16 = 48KB;
// tri-buffer 144KiB = R2's exact footprint; R2's exact sync skeleton
// (6 loads/thread/iter split 3+3, vmcnt(6), 1 barrier/K-tile; tail v0).
// A layout: row = 64 f32 = 16 chunks of 16B; LDS slot linear (g), source
// chunk col = c ^ (row&15) (involution); frag read applies same XOR.
// B layout identical to R2 (8 chunks/row, c ^ (row&7)).
// K-accumulation order (slice0 all, slice1 all, kt ascending) unchanged
// => bit-identical C, absmax 0.25.
__global__ __launch_bounds__(512, 1) void gemm_bt(
        const float* __restrict__ X,
        const unsigned short* __restrict__ B,
        float* __restrict__ C) {
    constexpr int K = IN, BK = 64, NT = K / BK;   // 16 K-steps
    constexpr int STG = 49152;                    // 48 KB (A-f32 32K + B 16K)
    constexpr int ES = 132;                       // epilogue row stride (floats)
    __shared__ __align__(16) char smem[3 * STG];  // 144 KiB
    float* ebuf = (float*)smem;                   // epilogue reuse (67.6 KB)

    const int tid  = threadIdx.x;
    const int bm   = blockIdx.x, bn = blockIdx.y;
    const int lane = tid & 63;
    const int wave = tid >> 6;     // 0..7
    const int wm   = wave >> 2;    // 0..1 along M
    const int wn   = wave & 3;     // 0..3 along N
    const int t    = lane & 15;
    const int q    = lane >> 4;
    const int r8   = t & 7;

    // ---- A staging map: 4 chunks/thread/K-step (2048 chunks of 16B) ----
    // chunk g: row = g>>4 (0..127), c = g&15; LDS slot = g (linear);
    // source f32 col = (c ^ (row&15)) * 4.
    int g0 = tid,         ar0 = g0 >> 4, ac0 = ((g0 & 15) ^ (ar0 & 15)) * 4;
    int g1 = 512 + tid,   ar1 = g1 >> 4, ac1 = ((g1 & 15) ^ (ar1 & 15)) * 4;
    int g2 = 1024 + tid,  ar2 = g2 >> 4, ac2 = ((g2 & 15) ^ (ar2 & 15)) * 4;
    int g3 = 1536 + tid,  ar3 = g3 >> 4, ac3 = ((g3 & 15) ^ (ar3 & 15)) * 4;
    // ---- B staging map: 2 chunks/thread/K-step (1024 chunks) ----
    int h0 = tid,         br0 = h0 >> 3, bc0 = ((h0 & 7) ^ (br0 & 7)) * 8;
    int h1 = 512 + tid,   br1 = h1 >> 3, bc1 = ((h1 & 7) ^ (br1 & 7)) * 8;

    const float* gx0 = X + (size_t)(bm * 128 + ar0) * K + ac0;
    const float* gx1 = X + (size_t)(bm * 128 + ar1) * K + ac1;
    const float* gx2 = X + (size_t)(bm * 128 + ar2) * K + ac2;
    const float* gx3 = X + (size_t)(bm * 128 + ar3) * K + ac3;
    const unsigned short* gB0 = B + (size_t)(bn * 128 + br0) * K + bc0;
    const unsigned short* gB1 = B + (size_t)(bn * 128 + br1) * K + bc1;

    const int dA0 = g0 * 16, dA1 = g1 * 16, dA2 = g2 * 16, dA3 = g3 * 16;
    const int dB0 = 32768 + h0 * 16, dB1 = 32768 + h1 * 16;

    // ---- A fragment byte offsets: row (wm*64 + i*16 + t), i stride 4096B.
    // slice s chunk-pair: logical {8s+2q, 8s+2q+1}, phys = logical ^ t.
    const int aRow = (wm * 64 + t) * 256;
    const int aL0 = aRow + (((0 + 2 * q) ^ t) * 16);       // s=0 low
    const int aH0 = aRow + (((1 + 2 * q) ^ t) * 16);       // s=0 high
    const int aL1 = aRow + (((8 + 2 * q) ^ t) * 16);       // s=1 low
    const int aH1 = aRow + (((9 + 2 * q) ^ t) * 16);       // s=1 high
    // ---- B fragment byte offsets: row (wn*32 + tn*16 + t), tn stride 2048B.
    const int bO0 = 32768 + ((wn * 32 + t) * 64 + ((0 + q) ^ r8) * 8) * 2;
    const int bO1 = 32768 + ((wn * 32 + t) * 64 + ((4 + q) ^ r8) * 8) * 2;

    floatx4 acc[4][2];
#pragma unroll
    for (int i = 0; i < 4; ++i)
#pragma unroll
        for (int j = 0; j < 2; ++j)
            acc[i][j] = (floatx4){0.f, 0.f, 0.f, 0.f};

#define STAGE_P(sp, ko)                                             \
    {                                                               \
        gload_lds16(gx0 + (ko), (sp) + dA0);                        \
        gload_lds16(gx1 + (ko), (sp) + dA1);                        \
        gload_lds16(gx2 + (ko), (sp) + dA2);                        \
    }
#define STAGE_Q(sp, ko)                                             \
    {                                                               \
        gload_lds16(gx3 + (ko), (sp) + dA3);                        \
        gload_lds16(gB0 + (ko), (sp) + dB0);                        \
        gload_lds16(gB1 + (ko), (sp) + dB1);                        \
    }
// One k-slice: 8 A f32x4 reads -> 4 bf16x8 frags (16 cvt_pk),
// 2 B b128 reads, 8 MFMA.
#define PHASE(sb, aL, aH, bO)                                       \
    {                                                               \
        const char* base = (const char*)(sb);                       \
        float4 l0 = *(const float4*)(base + (aL) + 0 * 4096);       \
        float4 h0_ = *(const float4*)(base + (aH) + 0 * 4096);      \
        float4 l1 = *(const float4*)(base + (aL) + 1 * 4096);       \
        float4 h1_ = *(const float4*)(base + (aH) + 1 * 4096);      \
        float4 l2 = *(const float4*)(base + (aL) + 2 * 4096);       \
        float4 h2_ = *(const float4*)(base + (aH) + 2 * 4096);      \
        float4 l3 = *(const float4*)(base + (aL) + 3 * 4096);       \
        float4 h3_ = *(const float4*)(base + (aH) + 3 * 4096);      \
        bf16x8 b0 = *(const bf16x8*)(base + (bO) + 0 * 2048);       \
        bf16x8 b1 = *(const bf16x8*)(base + (bO) + 1 * 2048);       \
        bf16x8 av[4] = {mkbf8(l0, h0_), mkbf8(l1, h1_),             \
                        mkbf8(l2, h2_), mkbf8(l3, h3_)};            \
        bf16x8 bv[2] = {b0, b1};                                    \
        __builtin_amdgcn_s_setprio(1);                              \
        _Pragma("unroll")                                           \
        for (int i = 0; i < 4; ++i)                                 \
            _Pragma("unroll")                                       \
            for (int j = 0; j < 2; ++j)                             \
                acc[i][j] = __builtin_amdgcn_mfma_f32_16x16x32_bf16(\
                    av[i], bv[j], acc[i][j], 0, 0, 0);              \
        __builtin_amdgcn_s_setprio(0);                              \
    }

    // ---- prologue: stage tiles 0 and 1, wait for tile 0 only ----
    {
        char* s0 = smem;
        char* s1 = smem + STG;
        STAGE_P(s0, 0); STAGE_Q(s0, 0);
        STAGE_P(s1, BK); STAGE_Q(s1, BK);
        WAIT_V6L0();       // tile 0 landed; tile 1's 6 loads in flight
        BARRIER();
    }

    int cur = 0;
    for (int kt = 0; kt < NT; ++kt) {
        char* sb = smem + cur * STG;
        int nx = cur + 2; if (nx >= 3) nx -= 3;
        char* sp = smem + nx * STG;
        const int kpre = (kt + 2) * BK;
        const bool pre = (kt < NT - 2);

        if (pre) STAGE_P(sp, kpre);
        PHASE(sb, aL0, aH0, bO0);      // k-slice 0
        if (pre) STAGE_Q(sp, kpre);
        PHASE(sb, aL1, aH1, bO1);      // k-slice 1

        if (pre) { WAIT_V6L0(); }      // tile kt+1 ready; kt+2 in flight
        else     { WAIT_V0L0(); }      // tail: drain
        BARRIER();
        ++cur; if (cur == 3) cur = 0;
    }
#undef PHASE
#undef STAGE_P
#undef STAGE_Q

    __syncthreads();   // full drain before LDS reuse as ebuf

    // ---- epilogue: dump 128x128 f32 via LDS (ES=132 pad), float4 out ----
    // D layout: col = t, row = q*4 + r  [m89/m91 verified]
#pragma unroll
    for (int tm = 0; tm < 4; ++tm)
#pragma unroll
        for (int tn = 0; tn < 2; ++tn)
#pragma unroll
            for (int r = 0; r < 4; ++r)
                ebuf[(wm * 64 + tm * 16 + q * 4 + r) * ES
                     + wn * 32 + tn * 16 + t] = acc[tm][tn][r];
    __syncthreads();
#pragma unroll
    for (int ps = 0; ps < 8; ++ps) {
        int row  = ps * 16 + (tid >> 5);
        int col4 = tid & 31;
        float4 v = *(const float4*)(ebuf + row * ES + col4 * 4);
        *(float4*)(C + (size_t)(bm * 128 + row) * OUTD + bn * 128 + col4 * 4) = v;
    }
}

extern "C" void kernel_launch(void* const* d_in, const int* in_sizes, int n_in,
                              void* d_out, int out_size, void* d_ws, size_t ws_size,
                              hipStream_t stream) {
    const float* x    = (const float*)d_in[0];
    const float* coef = (const float*)d_in[1];
    const float* w    = (const float*)d_in[2];
    float* out = (float*)d_out;

    unsigned short* weff = (unsigned short*)d_ws;   // 2 MB

    prep_kernel<<<2048, 256, 0, stream>>>(coef, w, weff);
    gemm_bt<<<dim3(BATCH / 128, OUTD / 128), 512, 0, stream>>>(x, weff, out);
}

// Round 12
// 124.281 us; speedup vs baseline: 1.2242x; 1.2242x over previous
//
#include <hip/hip_runtime.h>
#include <hip/hip_bf16.h>
#include <stdint.h>

#define BATCH 8192
#define IN    1024
#define OUTD  1024
#define PBASIS 8

typedef __attribute__((ext_vector_type(8))) short bf16x8;
typedef __attribute__((ext_vector_type(4))) float floatx4;

__device__ __forceinline__ unsigned short f2bf(float f) {
    union { float f; unsigned u; } v; v.f = f;
    unsigned u = v.u;
    u += 0x7fffu + ((u >> 16) & 1u);   // RNE; inputs finite randn
    return (unsigned short)(u >> 16);
}

// Fused prep: blocks [0,4096) convert x -> bf16 (8 elem/thread);
// blocks [4096,6144) compute w_eff = bf16(sum_p coef * w) (2 elem/thread).
__global__ void prep_kernel(const float* __restrict__ x,
                            const float* __restrict__ coef,
                            const float* __restrict__ w,
                            unsigned short* __restrict__ xb,
                            unsigned short* __restrict__ weff) {
    int b = blockIdx.x;
    int tid = threadIdx.x;
    if (b < 4096) {
        int idx = b * 256 + tid;
        const float4* p = (const float4*)(x + (size_t)idx * 8);
        float4 a = p[0], c = p[1];
        uint4 o;
        o.x = (unsigned)f2bf(a.x) | ((unsigned)f2bf(a.y) << 16);
        o.y = (unsigned)f2bf(a.z) | ((unsigned)f2bf(a.w) << 16);
        o.z = (unsigned)f2bf(c.x) | ((unsigned)f2bf(c.y) << 16);
        o.w = (unsigned)f2bf(c.z) | ((unsigned)f2bf(c.w) << 16);
        ((uint4*)xb)[idx] = o;
    } else {
        int idx = (b - 4096) * 256 + tid;   // element pair index
        size_t e0 = (size_t)idx * 2;
        const float4* c4 = (const float4*)(coef + e0 * PBASIS);
        float4 a = c4[0], bb = c4[1], c = c4[2], d = c4[3];
        float s0 = (a.x + a.y + a.z + a.w) + (bb.x + bb.y + bb.z + bb.w);
        float s1 = (c.x + c.y + c.z + c.w) + (d.x + d.y + d.z + d.w);
        float2 ww = ((const float2*)w)[idx];
        unsigned b0 = f2bf(s0 * ww.x);
        unsigned b1 = f2bf(s1 * ww.y);
        ((unsigned*)weff)[idx] = b0 | (b1 << 16);
    }
}

__device__ __forceinline__ void gload_lds16(const void* g, void* l) {
    __builtin_amdgcn_global_load_lds(
        (const __attribute__((address_space(1))) unsigned int*)g,
        (__attribute__((address_space(3))) unsigned int*)l,
        16, 0, 0);
}

// Raw barrier + counted waits (T3+T4): loads stay in flight across barriers.
#define BARRIER()  asm volatile("s_barrier" ::: "memory")
#define WAIT_V6L0() asm volatile("s_waitcnt vmcnt(6) lgkmcnt(0)" ::: "memory")
#define WAIT_V0L0() asm volatile("s_waitcnt vmcnt(0) lgkmcnt(0)" ::: "memory")

// C[m,n] = sum_k A[m,k]*B[n,k]; A=[8192,1024], B=[1024,1024] bf16, C f32.
// BM=256 x BN=128 tile, BK=64, 512 threads = 8 waves (4M x 2N), per-wave
// 64x64 out (4x4 frags of 16x16x32). Tri-buffered LDS (3 x 48KB = 144KB,
// 1 block/CU), grid 32x8 = 256 blocks = 1/CU. Pipeline: during tile kt,
// issue tile kt+2's 6 global_load_lds into stage (kt+2)%3 (freed by kt-1,
// whose reads completed before kt's ready-barrier), then wait vmcnt(6)
// (tile kt+1 landed; kt+2's 6 stay in flight) + lgkmcnt(0) (no ds_read
// crosses the barrier) + raw s_barrier. Never drains vmcnt to 0 in the
// main loop. SESSION VERDICT (R0-R11): this staging contract -- bf16
// operands staged ONLY by fire-and-forget global_load_lds, consumed
// directly as MFMA fragments -- is the fast family (gemm ~26.5us). Every
// deviation regressed 2-2.5x: B-direct-to-reg (R6, 49us), reg-cvt staging
// (R8/R9, 49us), T14 reorder (R10, 46us), f32-in-LDS + cvt-at-read (R11,
// 64us): hipcc sinks per-lane VMEM consumers to their use, serializing
// prefetch. T1 XCD swizzle hurts (L3-resident working set, R5). Smaller
// 2-block/CU tile neutral (R7).
__global__ __launch_bounds__(512, 2) void gemm_bt(
        const unsigned short* __restrict__ A,
        const unsigned short* __restrict__ B,
        float* __restrict__ C) {
    constexpr int K = IN, BK = 64, NT = K / BK;   // 16 K-steps
    constexpr int STG = 49152;                    // 48 KB per stage (A 32K + B 16K)
    constexpr int ES = 132;                       // epilogue row stride (floats)
    __shared__ __align__(16) char smem[3 * STG];  // 144 KiB
    float* ebuf = (float*)smem;                   // epilogue reuse (256*132*4 = 132K)

    const int tid  = threadIdx.x;
    const int bm   = blockIdx.x, bn = blockIdx.y;
    const int lane = tid & 63;
    const int wave = tid >> 6;     // 0..7
    const int wm   = wave >> 1;    // 0..3 along M
    const int wn   = wave & 1;     // 0..1 along N
    const int t    = lane & 15;    // M/N index within 16
    const int q    = lane >> 4;    // K-quad
    const int r8   = t & 7;        // XOR swizzle key

    // ---- staging map: 6 chunks/thread/K-step (A: j=0..3, B: j=0..1) ----
    // chunk g: row = g>>3, c = g&7; LDS slot = g (linear, required by
    // global_load_lds); global source column = c ^ (row&7) (involution).
    int g0 = tid,        ra0 = g0 >> 3, ca0 = (g0 & 7) ^ (ra0 & 7);
    int g1 = 512 + tid,  ra1 = g1 >> 3, ca1 = (g1 & 7) ^ (ra1 & 7);
    int g2 = 1024 + tid, ra2 = g2 >> 3, ca2 = (g2 & 7) ^ (ra2 & 7);
    int g3 = 1536 + tid, ra3 = g3 >> 3, ca3 = (g3 & 7) ^ (ra3 & 7);
    int h0 = tid,        rb0 = h0 >> 3, cb0 = (h0 & 7) ^ (rb0 & 7);
    int h1 = 512 + tid,  rb1 = h1 >> 3, cb1 = (h1 & 7) ^ (rb1 & 7);

    const unsigned short* gA0 = A + (size_t)(bm * 256 + ra0) * K + ca0 * 8;
    const unsigned short* gA1 = A + (size_t)(bm * 256 + ra1) * K + ca1 * 8;
    const unsigned short* gA2 = A + (size_t)(bm * 256 + ra2) * K + ca2 * 8;
    const unsigned short* gA3 = A + (size_t)(bm * 256 + ra3) * K + ca3 * 8;
    const unsigned short* gB0 = B + (size_t)(bn * 128 + rb0) * K + cb0 * 8;
    const unsigned short* gB1 = B + (size_t)(bn * 128 + rb1) * K + cb1 * 8;

    const int dA0 = g0 * 16, dA1 = g1 * 16, dA2 = g2 * 16, dA3 = g3 * 16;
    const int dB0 = 32768 + h0 * 16, dB1 = 32768 + h1 * 16;

    // ---- fragment byte offsets within a stage (A at 0, B at 32768) ----
    const int aO0 = ((wm * 64 + t) * 64 + ((0 + q) ^ r8) * 8) * 2;
    const int aO1 = ((wm * 64 + t) * 64 + ((4 + q) ^ r8) * 8) * 2;
    const int bO0 = 32768 + ((wn * 64 + t) * 64 + ((0 + q) ^ r8) * 8) * 2;
    const int bO1 = 32768 + ((wn * 64 + t) * 64 + ((4 + q) ^ r8) * 8) * 2;

    floatx4 acc[4][4];
#pragma unroll
    for (int i = 0; i < 4; ++i)
#pragma unroll
        for (int j = 0; j < 4; ++j)
            acc[i][j] = (floatx4){0.f, 0.f, 0.f, 0.f};

#define STAGE_A3(sp, ko)                                            \
    {                                                               \
        gload_lds16(gA0 + (ko), (sp) + dA0);                        \
        gload_lds16(gA1 + (ko), (sp) + dA1);                        \
        gload_lds16(gA2 + (ko), (sp) + dA2);                        \
    }
#define STAGE_B3(sp, ko)                                            \
    {                                                               \
        gload_lds16(gA3 + (ko), (sp) + dA3);                        \
        gload_lds16(gB0 + (ko), (sp) + dB0);                        \
        gload_lds16(gB1 + (ko), (sp) + dB1);                        \
    }
// One phase: 8 ds_read_b128 (4 A frags + 4 B frags, one k-slice) + 16 MFMA.
#define PHASE(sb, aO, bO)                                           \
    {                                                               \
        const char* ab = (const char*)(sb) + (aO);                  \
        const char* bb = (const char*)(sb) + (bO);                  \
        bf16x8 af0 = *(const bf16x8*)(ab + 0 * 2048);               \
        bf16x8 af1 = *(const bf16x8*)(ab + 1 * 2048);               \
        bf16x8 af2 = *(const bf16x8*)(ab + 2 * 2048);               \
        bf16x8 af3 = *(const bf16x8*)(ab + 3 * 2048);               \
        bf16x8 bf0 = *(const bf16x8*)(bb + 0 * 2048);               \
        bf16x8 bf1 = *(const bf16x8*)(bb + 1 * 2048);               \
        bf16x8 bf2 = *(const bf16x8*)(bb + 2 * 2048);               \
        bf16x8 bf3 = *(const bf16x8*)(bb + 3 * 2048);               \
        bf16x8 afv[4] = {af0, af1, af2, af3};                       \
        bf16x8 bfv[4] = {bf0, bf1, bf2, bf3};                       \
        __builtin_amdgcn_s_setprio(1);                              \
        _Pragma("unroll")                                           \
        for (int i = 0; i < 4; ++i)                                 \
            _Pragma("unroll")                                       \
            for (int j = 0; j < 4; ++j)                             \
                acc[i][j] = __builtin_amdgcn_mfma_f32_16x16x32_bf16(\
                    afv[i], bfv[j], acc[i][j], 0, 0, 0);            \
        __builtin_amdgcn_s_setprio(0);                              \
    }

    // ---- prologue: stage tiles 0 and 1, wait for tile 0 only ----
    {
        char* s0 = smem;
        char* s1 = smem + STG;
        STAGE_A3(s0, 0); STAGE_B3(s0, 0);
        STAGE_A3(s1, BK); STAGE_B3(s1, BK);
        WAIT_V6L0();       // tile 0 landed; tile 1's 6 loads in flight
        BARRIER();
    }

    int cur = 0;
    for (int kt = 0; kt < NT; ++kt) {
        char* sb = smem + cur * STG;
        int nx = cur + 2; if (nx >= 3) nx -= 3;
        char* sp = smem + nx * STG;
        const int kpre = (kt + 2) * BK;
        const bool pre = (kt < NT - 2);

        if (pre) STAGE_A3(sp, kpre);
        PHASE(sb, aO0, bO0);           // k-slice 0
        if (pre) STAGE_B3(sp, kpre);
        PHASE(sb, aO1, bO1);           // k-slice 1

        if (pre) { WAIT_V6L0(); }      // tile kt+1 ready; kt+2 in flight
        else     { WAIT_V0L0(); }      // tail: drain
        BARRIER();
        ++cur; if (cur == 3) cur = 0;
    }
#undef PHASE
#undef STAGE_A3
#undef STAGE_B3

    __syncthreads();   // full drain before LDS reuse as ebuf

    // ---- epilogue: dump 256x128 f32 via LDS (ES=132 pad), float4 out ----
    // D layout: col = t, row = q*4 + r  [m89/m91 verified]
#pragma unroll
    for (int tm = 0; tm < 4; ++tm)
#pragma unroll
        for (int tn = 0; tn < 4; ++tn)
#pragma unroll
            for (int r = 0; r < 4; ++r)
                ebuf[(wm * 64 + tm * 16 + q * 4 + r) * ES
                     + wn * 64 + tn * 16 + t] = acc[tm][tn][r];
    __syncthreads();
#pragma unroll
    for (int ps = 0; ps < 16; ++ps) {
        int row  = ps * 16 + (tid >> 5);
        int col4 = tid & 31;
        float4 v = *(const float4*)(ebuf + row * ES + col4 * 4);
        *(float4*)(C + (size_t)(bm * 256 + row) * OUTD + bn * 128 + col4 * 4) = v;
    }
}

extern "C" void kernel_launch(void* const* d_in, const int* in_sizes, int n_in,
                              void* d_out, int out_size, void* d_ws, size_t ws_size,
                              hipStream_t stream) {
    const float* x    = (const float*)d_in[0];
    const float* coef = (const float*)d_in[1];
    const float* w    = (const float*)d_in[2];
    float* out = (float*)d_out;

    unsigned short* xb   = (unsigned short*)d_ws;                                   // 16 MB
    unsigned short* weff = (unsigned short*)((char*)d_ws + (size_t)BATCH * IN * 2); // +2 MB

    prep_kernel<<<6144, 256, 0, stream>>>(x, coef, w, xb, weff);
    gemm_bt<<<dim3(BATCH / 256, OUTD / 128), 512, 0, stream>>>(xb, weff, out);
}